// Round 1
// baseline (545.116 us; speedup 1.0000x reference)
//
#include <hip/hip_runtime.h>

// SparseShiftGateRecurrence: h[t] = alpha*h[t-1] + beta*x[t] on channels [0,512),
// passthrough on [512,2048). B=8, S=4096, D=2048, fp32.
//
// Strategy: alpha=0.9 is contractive -> split each (b,channel) chain of S=4096
// into NCHUNK=8 chunks of CHUNK=512 steps. Each chunk warms up from h=0 over
// WARM=256 preceding steps; truncation error = 0.9^256 * |h| ~ 1e-12 (exact
// for chunk 0). This turns 4096 serial chains into 8192 parallel float4 threads.
// Passthrough channels are a straight float4 copy in the same kernel (copy
// blocks follow rec blocks in dispatch order so rec waves start first and the
// copy fills HBM bandwidth around them).

#define BATCH   8
#define SEQ     4096
#define DIM     2048
#define ACTIVE  512
#define ROWQ    (DIM / 4)       // 512 float4 per (b,s) row
#define CHUNK   512
#define WARM    256
#define NCHUNK  (SEQ / CHUNK)   // 8
#define GROUPS  (ACTIVE / 4)    // 128 float4 channel-groups
#define REC_THREADS (NCHUNK * BATCH * GROUPS)   // 8192
#define REC_BLOCKS  (REC_THREADS / 256)         // 32
#define COPY_ROWS   (BATCH * SEQ)               // 32768
#define ROWS_PER_BLOCK 4
#define COPY_BLOCKS (COPY_ROWS / ROWS_PER_BLOCK) // 8192

__global__ __launch_bounds__(256) void ssgr_kernel(
    const float* __restrict__ x,
    const float* __restrict__ alpha,
    const float* __restrict__ beta,
    float* __restrict__ out) {
  const float4* __restrict__ x4 = reinterpret_cast<const float4*>(x);
  float4* __restrict__ out4 = reinterpret_cast<float4*>(out);
  const int bi = blockIdx.x;

  if (bi < REC_BLOCKS) {
    // ---- recurrence blocks: one thread per (chunk, batch, channel-group) ----
    const int r  = bi * 256 + threadIdx.x;       // 0..8191
    const int g  = r & (GROUPS - 1);             // channel group: lanes consecutive -> coalesced
    const int b  = (r >> 7) & (BATCH - 1);
    const int ci = r >> 10;                      // chunk index 0..7

    const float4 al = reinterpret_cast<const float4*>(alpha)[g];
    const float4 be = reinterpret_cast<const float4*>(beta)[g];

    const int t0 = ci * CHUNK;
    int tstart = t0 - WARM;
    if (tstart < 0) tstart = 0;

    const long rowbase = (long)b * SEQ;
    const float4* xp = x4 + (rowbase + tstart) * ROWQ + g;

    float4 h = make_float4(0.f, 0.f, 0.f, 0.f);

    // warmup (empty for chunk 0 -> exact there; ~1e-12 truncation elsewhere)
    #pragma unroll 8
    for (int t = tstart; t < t0; ++t) {
      float4 v = *xp; xp += ROWQ;
      h.x = al.x * h.x + be.x * v.x;
      h.y = al.y * h.y + be.y * v.y;
      h.z = al.z * h.z + be.z * v.z;
      h.w = al.w * h.w + be.w * v.w;
    }

    float4* op = out4 + (rowbase + t0) * ROWQ + g;
    #pragma unroll 4
    for (int t = 0; t < CHUNK; ++t) {
      float4 v = *xp; xp += ROWQ;
      h.x = al.x * h.x + be.x * v.x;
      h.y = al.y * h.y + be.y * v.y;
      h.z = al.z * h.z + be.z * v.z;
      h.w = al.w * h.w + be.w * v.w;
      *op = h; op += ROWQ;
    }
  } else {
    // ---- passthrough copy blocks: one wave per (b,s) row tail of 1536 floats ----
    const int row  = (bi - REC_BLOCKS) * ROWS_PER_BLOCK + (threadIdx.x >> 6);
    const int lane = threadIdx.x & 63;
    const float4* __restrict__ src = x4   + (long)row * ROWQ + (ACTIVE / 4);
    float4* __restrict__ dst       = out4 + (long)row * ROWQ + (ACTIVE / 4);
    #pragma unroll
    for (int k = 0; k < 6; ++k) {        // 384 float4 per row / 64 lanes
      dst[lane + 64 * k] = src[lane + 64 * k];
    }
  }
}

extern "C" void kernel_launch(void* const* d_in, const int* in_sizes, int n_in,
                              void* d_out, int out_size, void* d_ws, size_t ws_size,
                              hipStream_t stream) {
  const float* x     = (const float*)d_in[0];
  const float* alpha = (const float*)d_in[1];
  const float* beta  = (const float*)d_in[2];
  float* out = (float*)d_out;
  (void)in_sizes; (void)n_in; (void)out_size; (void)d_ws; (void)ws_size;

  dim3 grid(REC_BLOCKS + COPY_BLOCKS);
  dim3 block(256);
  hipLaunchKernelGGL(ssgr_kernel, grid, block, 0, stream, x, alpha, beta, out);
}